// Round 5
// baseline (1881.613 us; speedup 1.0000x reference)
//
#include <hip/hip_runtime.h>
#include <cstdint>

#define S_LEN 32768
#define NV 256
#define NH 512
#define NR 256
#define CD_K 5

typedef short bf16x8 __attribute__((ext_vector_type(8)));
typedef float f32x4 __attribute__((ext_vector_type(4)));
typedef unsigned short ushort_t;
typedef ushort_t u16x8 __attribute__((ext_vector_type(8)));

// ---------------- bf16 helpers (bit-level, RTNE) ----------------
__device__ __forceinline__ float b2f(ushort_t u) {
  return __uint_as_float(((uint32_t)u) << 16);
}
__device__ __forceinline__ ushort_t f2b(float f) {
  uint32_t x = __float_as_uint(f);
  uint32_t r = (x + 0x7fffu + ((x >> 16) & 1u)) >> 16;
  return (ushort_t)r;
}

// ---------------- host-side threefry2x32 (key-chain derivation only) ----------------
#define TFR(x0,x1,r) { x0 += x1; x1 = ((x1 << (r)) | (x1 >> (32 - (r)))); x1 ^= x0; }
__host__ __forceinline__ void tf2x32(uint32_t k0, uint32_t k1,
                                     uint32_t x0, uint32_t x1,
                                     uint32_t* o0, uint32_t* o1) {
  uint32_t k2 = k0 ^ k1 ^ 0x1BD11BDAu;
  x0 += k0; x1 += k1;
  TFR(x0,x1,13) TFR(x0,x1,15) TFR(x0,x1,26) TFR(x0,x1,6)
  x0 += k1; x1 += k2 + 1u;
  TFR(x0,x1,17) TFR(x0,x1,29) TFR(x0,x1,16) TFR(x0,x1,24)
  x0 += k2; x1 += k0 + 2u;
  TFR(x0,x1,13) TFR(x0,x1,15) TFR(x0,x1,26) TFR(x0,x1,6)
  x0 += k0; x1 += k1 + 3u;
  TFR(x0,x1,17) TFR(x0,x1,29) TFR(x0,x1,16) TFR(x0,x1,24)
  x0 += k1; x1 += k2 + 4u;
  TFR(x0,x1,13) TFR(x0,x1,15) TFR(x0,x1,26) TFR(x0,x1,6)
  x0 += k2; x1 += k0 + 5u;
  *o0 = x0; *o1 = x1;
}

// ---------------- device RNG: murmur3 full-avalanche counter hash (~11 VALU) --------
__device__ __forceinline__ float fast_uniform(uint32_t k0, uint32_t k1, uint32_t idx) {
  uint32_t h = idx ^ k0;
  h *= 0xCC9E2D51u; h = (h << 15) | (h >> 17); h *= 0x1B873593u;
  h ^= k1;
  h ^= h >> 16; h *= 0x85EBCA6Bu;
  h ^= h >> 13; h *= 0xC2B2AE35u;
  h ^= h >> 16;
  return __uint_as_float((h >> 9) | 0x3f800000u) - 1.0f;
}

__device__ __forceinline__ float wave_reduce(float v) {
#pragma unroll
  for (int o = 32; o > 0; o >>= 1) v += __shfl_down(v, o, 64);
  return v;
}

// ---------------- epilogue flags ----------------
#define F_F32   1
#define F_B16   2
#define F_SAMP  4
#define F_H1    8
#define F_FE    16
#define F_MON   32

// ---------------- bf16 MFMA GEMM: C[M,N] = A[M,K] @ BT[N,K]^T + bias, fused epilogue --
// 128x128 tile, BK=64, 256 threads (4 waves as 2x2), mfma_f32_16x16x32_bf16.
// K-loop LDS: [128 rows][64 bf16], 16B-block XOR swizzle (phys b = b ^ (r&7)).
// Epilogue v2: MFMA C-layout is column-fragmented (quad = row group), which forced
// 64 scalar 2B loads + 64 scalar 2B stores per thread in v1 (round-3 counters:
// MfmaUtil 1.8%, VALUBusy 26% -> VMEM-instr/latency bound). Now: 4 passes of a
// 32x128 f32 LDS transpose (union with staging LDS, +4 row pad) so each thread
// owns 16 row-contiguous outputs -> b128 vector IO. RNG element index unchanged.
// ldc = row stride of C/C2/Cf/vseq; ldbias = row stride of biasm.
template<int FLAGS, bool BIASMAT>
__global__ __launch_bounds__(256)
void gemm_bf16(const ushort_t* __restrict__ A, const ushort_t* __restrict__ BT,
               const float* __restrict__ biasv, const ushort_t* __restrict__ biasm,
               int ldbias,
               ushort_t* __restrict__ C, ushort_t* __restrict__ C2,
               float* __restrict__ Cf, const float* __restrict__ vseq,
               double* __restrict__ fe_acc, double* __restrict__ mon_acc, float sign,
               uint32_t rk0, uint32_t rk1, int M, int N, int K, int ldc) {
  __shared__ union {
    struct { ushort_t A[128 * 64]; ushort_t B[128 * 64]; } st;  // 32 KB staging
    float cbuf[32 * 132];                                        // 16.9 KB transpose
  } sh;
  const int tid = threadIdx.x;
  const int lane = tid & 63, wave = tid >> 6;
  const int wm = wave >> 1, wn = wave & 1;
  const int q = lane >> 4, l16 = lane & 15;
  const int m0 = blockIdx.y * 128, n0 = blockIdx.x * 128;

  f32x4 acc[4][4];
#pragma unroll
  for (int i = 0; i < 4; i++)
#pragma unroll
    for (int j = 0; j < 4; j++) acc[i][j] = (f32x4){0.f, 0.f, 0.f, 0.f};

  for (int kk = 0; kk < K; kk += 64) {
#pragma unroll
    for (int j = 0; j < 4; j++) {
      int c = j * 256 + tid;
      int r = c >> 3, bl = c & 7, bg = bl ^ (r & 7);
      *(uint4*)&sh.st.A[r * 64 + bl * 8] =
          *(const uint4*)&A[(size_t)(m0 + r) * K + kk + bg * 8];
      *(uint4*)&sh.st.B[r * 64 + bl * 8] =
          *(const uint4*)&BT[(size_t)(n0 + r) * K + kk + bg * 8];
    }
    __syncthreads();
#pragma unroll
    for (int c = 0; c < 2; c++) {
      bf16x8 af[4], bf[4];
#pragma unroll
      for (int mt = 0; mt < 4; mt++) {
        int r = wm * 64 + mt * 16 + l16;
        af[mt] = *(const bf16x8*)&sh.st.A[r * 64 + (((c * 4 + q) ^ (r & 7)) * 8)];
      }
#pragma unroll
      for (int nt = 0; nt < 4; nt++) {
        int r = wn * 64 + nt * 16 + l16;
        bf[nt] = *(const bf16x8*)&sh.st.B[r * 64 + (((c * 4 + q) ^ (r & 7)) * 8)];
      }
#pragma unroll
      for (int mt = 0; mt < 4; mt++)
#pragma unroll
        for (int nt = 0; nt < 4; nt++)
          acc[mt][nt] = __builtin_amdgcn_mfma_f32_16x16x32_bf16(
              af[mt], bf[nt], acc[mt][nt], 0, 0, 0);
    }
    __syncthreads();
  }

  // ---- epilogue v2 ----
  float fe_sum = 0.f, mon_sum = 0.f;
  const int lrow_r = tid >> 3;                       // 0..31
  const int cs_r = (tid & 7) * 16;                   // col base, 16B-aligned reads
  const int gm_base = m0 + (lrow_r >> 4) * 64 + (lrow_r & 15);
  const int gnb = n0 + cs_r;

#pragma unroll
  for (int mt = 0; mt < 4; mt++) {
    __syncthreads();  // cbuf free (K-loop done / previous pass reads done)
#pragma unroll
    for (int nt = 0; nt < 4; nt++) {
      const int lr = wm * 16 + q * 4;
      const int col = wn * 64 + nt * 16 + l16;
#pragma unroll
      for (int rg = 0; rg < 4; rg++)
        sh.cbuf[(lr + rg) * 132 + col] = acc[mt][nt][rg];
    }
    __syncthreads();
    const int gm = gm_base + mt * 16;
    const int rdbase = lrow_r * 132 + cs_r;

#pragma unroll
    for (int h = 0; h < 2; h++) {  // two 8-wide chunks
      f32x4 za = *(const f32x4*)&sh.cbuf[rdbase + h * 8];
      f32x4 zb = *(const f32x4*)&sh.cbuf[rdbase + h * 8 + 4];
      float z[8] = {za[0], za[1], za[2], za[3], zb[0], zb[1], zb[2], zb[3]};
      if constexpr (BIASMAT) {
        u16x8 bb = *(const u16x8*)&biasm[(size_t)gm * ldbias + gnb + h * 8];
#pragma unroll
        for (int i = 0; i < 8; i++) z[i] += b2f(bb[i]);
      } else {
        f32x4 ba = *(const f32x4*)&biasv[gnb + h * 8];
        f32x4 bb4 = *(const f32x4*)&biasv[gnb + h * 8 + 4];
#pragma unroll
        for (int i = 0; i < 4; i++) { z[i] += ba[i]; z[4 + i] += bb4[i]; }
      }
      const size_t obase = (size_t)gm * ldc + gnb + h * 8;
      if constexpr (FLAGS & F_F32) {
        f32x4 oa = {z[0], z[1], z[2], z[3]}, ob = {z[4], z[5], z[6], z[7]};
        *(f32x4*)&Cf[obase] = oa;
        *(f32x4*)&Cf[obase + 4] = ob;
      }
      if constexpr (FLAGS & F_B16) {
        u16x8 o;
#pragma unroll
        for (int i = 0; i < 8; i++) o[i] = f2b(z[i]);
        *(u16x8*)&C[obase] = o;
      }
      if constexpr (FLAGS & (F_SAMP | F_H1 | F_MON)) {
        float e[8], p[8];
#pragma unroll
        for (int i = 0; i < 8; i++) e[i] = __expf(-z[i]);
        if constexpr (FLAGS & (F_H1 | F_MON))
#pragma unroll
          for (int i = 0; i < 8; i++) p[i] = __builtin_amdgcn_rcpf(1.f + e[i]);
        if constexpr (FLAGS & F_SAMP) {
          const uint32_t ibase = (uint32_t)((size_t)gm * N + gnb + h * 8);
          u16x8 o;
#pragma unroll
          for (int i = 0; i < 8; i++) {
            float u = fast_uniform(rk0, rk1, ibase + i);
            // u < sigmoid(z)  <=>  u*(1+e^-z) < 1
            o[i] = (fmaf(u, e[i], u) < 1.f) ? (ushort_t)0x3f80 : (ushort_t)0;
          }
          *(u16x8*)&C[obase] = o;
        }
        if constexpr (FLAGS & F_H1) {
          u16x8 o;
#pragma unroll
          for (int i = 0; i < 8; i++) o[i] = f2b(p[i]);
          *(u16x8*)&C2[obase] = o;
        }
        if constexpr (FLAGS & F_MON) {
          f32x4 va = *(const f32x4*)&vseq[obase];
          f32x4 vb = *(const f32x4*)&vseq[obase + 4];
          float v[8] = {va[0], va[1], va[2], va[3], vb[0], vb[1], vb[2], vb[3]};
#pragma unroll
          for (int i = 0; i < 8; i++)
            mon_sum += (v[i] != 0.f) ? logf(p[i] + 1e-10f)
                                     : logf(1.f - p[i] + 1e-10f);
        }
      }
      if constexpr (FLAGS & F_FE)
#pragma unroll
        for (int i = 0; i < 8; i++)
          fe_sum += fmaxf(z[i], 0.f) + log1pf(expf(-fabsf(z[i])));
    }
  }
  if constexpr (FLAGS & F_FE) {
    float s = wave_reduce(fe_sum);
    if (lane == 0) atomicAdd(fe_acc, (double)(-sign * s));
  }
  if constexpr (FLAGS & F_MON) {
    float s = wave_reduce(mon_sum);
    if (lane == 0) atomicAdd(mon_acc, (double)s);
  }
}

// ---------------- chunked RNN scan v3 ----------------
// ||Wuu||_2 ~ 0.32 -> 32-step warmup error ~1e-16 (exact at f32).
// Round-4 counters: SQ_LDS_BANK_CONFLICT 4.2e7/dispatch = ~4 extra cyc on EVERY
// ds_read_b128: even lanes read u[qq], odd lanes u[128+qq], and 128%32==0 ->
// same bank set. Fix: second half at offset 132 (banks shifted by 4 -> disjoint).
__global__ __launch_bounds__(512, 2)
void rnn_scan(const float* __restrict__ Apre, const float* __restrict__ Wuu,
              ushort_t* __restrict__ shifted) {
  const int tid = threadIdx.x;
  const int j = tid >> 1;
  const int s = tid & 1;
  const int t_begin = blockIdx.x * 128;
  const int t_end = t_begin + 128;
  const int t0 = (t_begin >= 32) ? (t_begin - 32) : 0;

  float w[128];
#pragma unroll
  for (int i = 0; i < 128; i++) w[i] = Wuu[(size_t)(s * 128 + i) * 256 + j];

  __shared__ float u[2][264];   // halves at 0 and 132 (+4 pad -> disjoint banks)
  __shared__ float asg[16 * 256];
  if (tid < 256) u[0][tid + (tid >> 7) * 4] = 0.f;
  if (blockIdx.x == 0 && s == 0) shifted[j] = 0;  // shifted[0,:] = 0
  __syncthreads();

  const int jp = j + (j >> 7) * 4;   // physical index of j in padded u
  int p = 0;
  for (int tb = t0; tb < t_end; tb += 16) {
    float4 a0 = *(const float4*)&Apre[(size_t)tb * 256 + tid * 8];
    float4 a1 = *(const float4*)&Apre[(size_t)tb * 256 + tid * 8 + 4];
    *(float4*)&asg[tid * 8] = a0;
    *(float4*)&asg[tid * 8 + 4] = a1;
    __syncthreads();
#pragma unroll 1
    for (int i = 0; i < 16; i++) {
      const int t = tb + i;
      float p0 = 0.f, p1 = 0.f, p2 = 0.f, p3 = 0.f;
#pragma unroll
      for (int qq = 0; qq < 128; qq += 4) {
        float4 uv = *(const float4*)&u[p][s * 132 + qq];
        p0 = fmaf(uv.x, w[qq + 0], p0);
        p1 = fmaf(uv.y, w[qq + 1], p1);
        p2 = fmaf(uv.z, w[qq + 2], p2);
        p3 = fmaf(uv.w, w[qq + 3], p3);
      }
      float ps = (p0 + p1) + (p2 + p3);
      ps += __shfl_xor(ps, 1, 64);            // combine the two 128-halves
      float z = asg[i * 256 + j] + ps;
      float e = __expf(2.f * z);              // fast tanh
      float unew = 1.f - 2.f * __builtin_amdgcn_rcpf(e + 1.f);
      if (s == 0) {
        u[1 - p][jp] = unew;
        if (t >= t_begin && (t + 1) < S_LEN)
          shifted[(size_t)(t + 1) * 256 + j] = f2b(unew);
      }
      __syncthreads();
      p ^= 1;
    }
  }
}

// ---------------- prep: f32 -> bf16 convert / transpose-convert ----------------
__global__ __launch_bounds__(256)
void conv_b16(const float* __restrict__ src, ushort_t* __restrict__ dst, int n) {
  int i = blockIdx.x * 256 + threadIdx.x;
  if (i < n) dst[i] = f2b(src[i]);
}
__global__ __launch_bounds__(256)
void transp_b16(const float* __restrict__ src, ushort_t* __restrict__ dst, int R, int C) {
  int i = blockIdx.x * 256 + threadIdx.x;
  if (i < R * C) {
    int r = i / C, c = i - r * C;
    dst[(size_t)c * R + r] = f2b(src[i]);
  }
}

// ---------------- FE dot terms: acc += -sign * sum(x * b_strided) ----------------
__global__ __launch_bounds__(256)
void dot_b16(const ushort_t* __restrict__ x, const ushort_t* __restrict__ b, int n,
             int shift, int ldb, int boff, float sign, double* __restrict__ acc) {
  float s = 0.f;
  const int cmask = (1 << shift) - 1;
  for (int i = blockIdx.x * 256 + threadIdx.x; i < n; i += gridDim.x * 256) {
    int r = i >> shift, c = i & cmask;
    s += b2f(x[i]) * b2f(b[(size_t)r * ldb + boff + c]);
  }
  s = wave_reduce(s);
  if ((threadIdx.x & 63) == 0) atomicAdd(acc, (double)(-sign * s));
}

__global__ void finalize_kernel(const double* __restrict__ acc, float* __restrict__ out) {
  out[0] = (float)(acc[0] / (double)S_LEN);
  out[1] = (float)(acc[1] / (double)S_LEN);
}

// ---------------- host orchestration ----------------
extern "C" void kernel_launch(void* const* d_in, const int* in_sizes, int n_in,
                              void* d_out, int out_size, void* d_ws, size_t ws_size,
                              hipStream_t stream) {
  (void)in_sizes; (void)n_in; (void)out_size; (void)ws_size;
  const float* v_seq = (const float*)d_in[0];
  const float* W1    = (const float*)d_in[1];
  const float* bv    = (const float*)d_in[2];
  const float* bh1   = (const float*)d_in[3];
  const float* W2    = (const float*)d_in[4];
  const float* bh2   = (const float*)d_in[5];
  const float* Wyv   = (const float*)d_in[6];
  const float* Wyh1  = (const float*)d_in[7];
  const float* Wyh2  = (const float*)d_in[8];
  const float* Wvu   = (const float*)d_in[9];
  const float* Wuu   = (const float*)d_in[10];
  const float* bu    = (const float*)d_in[11];
  float* out = (float*)d_out;

  // ---- workspace layout (~220 MB), 256B-aligned ----
  const size_t SN = (size_t)S_LEN * NV;     // 8.4M
  const size_t SH = (size_t)S_LEN * NH;     // 16.8M
  const int NB = NV + NH + NH;              // 1280 concat bias cols
  char* base = (char*)d_ws;
  size_t cur = 0;
  auto take = [&](size_t bytes) { size_t o = cur; cur += (bytes + 255) & ~(size_t)255; return o; };
  double*   acc      = (double*)  (base + take(64));             // [0]=cost,[1]=monitor
  ushort_t* BTwvu    = (ushort_t*)(base + take(65536 * 2));      // Wvu^T  [256,256]
  ushort_t* Wycat    = (ushort_t*)(base + take((size_t)NB * NR * 2)); // [1280,256]
  float*    bveccat  = (float*)   (base + take(NB * 4));         // bv|bh1|bh2
  ushort_t* BTw1     = (ushort_t*)(base + take(131072 * 2));     // W1^T   [512,256]
  ushort_t* BTw1t    = (ushort_t*)(base + take(131072 * 2));     // W1     [256,512]
  ushort_t* BTw2     = (ushort_t*)(base + take(262144 * 2));     // W2^T   [512,512]
  ushort_t* BTw2t    = (ushort_t*)(base + take(262144 * 2));     // W2     [512,512]
  ushort_t* vseq_bf  = (ushort_t*)(base + take(SN * 2));
  ushort_t* shifted  = (ushort_t*)(base + take(SN * 2));
  ushort_t* bias_cat = (ushort_t*)(base + take((size_t)S_LEN * NB * 2)); // [S,1280]
  ushort_t* h1buf    = (ushort_t*)(base + take(SH * 2));
  ushort_t* sampA    = (ushort_t*)(base + take(SH * 2));
  ushort_t* sampB    = (ushort_t*)(base + take(SH * 2));
  // Arnn (f32 [S,256] = 33.5MB) aliases bias_cat (83.9MB): consumed by rnn_scan
  // before the cat bias GEMM overwrites the region.
  float* Arnn = (float*)bias_cat;

  // ---- per-event key derivation (host threefry chain, jax-style splits) ----
  uint32_t K0 = 0u, K1 = 42u;
  uint32_t kk0[20], kk1[20];
  for (int it = 0; it < 10; it++) {
    uint32_t n0, n1, a0, a1, b0, b1;
    tf2x32(K0, K1, 0u, 0u, &n0, &n1);
    tf2x32(K0, K1, 0u, 1u, &a0, &a1);
    tf2x32(K0, K1, 0u, 2u, &b0, &b1);
    kk0[2 * it] = a0; kk1[2 * it] = a1;
    kk0[2 * it + 1] = b0; kk1[2 * it + 1] = b1;
    K0 = n0; K1 = n1;
  }

  hipMemsetAsync(acc, 0, 2 * sizeof(double), stream);

  dim3 blk(256);
  // ---- prep ----
  conv_b16<<<dim3((int)((SN + 255) / 256)), blk, 0, stream>>>(v_seq, vseq_bf, (int)SN);
  conv_b16<<<dim3(256), blk, 0, stream>>>(Wyv, Wycat, 65536);                 // rows 0..255
  conv_b16<<<dim3(512), blk, 0, stream>>>(Wyh1, Wycat + 65536, 131072);       // rows 256..767
  conv_b16<<<dim3(512), blk, 0, stream>>>(Wyh2, Wycat + 196608, 131072);      // rows 768..1279
  conv_b16<<<dim3(512), blk, 0, stream>>>(W1, BTw1t, 131072);
  conv_b16<<<dim3(1024), blk, 0, stream>>>(W2, BTw2t, 262144);
  transp_b16<<<dim3(256), blk, 0, stream>>>(Wvu, BTwvu, 256, 256);
  transp_b16<<<dim3(512), blk, 0, stream>>>(W1, BTw1, 256, 512);
  transp_b16<<<dim3(1024), blk, 0, stream>>>(W2, BTw2, 512, 512);
  hipMemcpyAsync(bveccat,        bv,  NV * 4, hipMemcpyDeviceToDevice, stream);
  hipMemcpyAsync(bveccat + NV,   bh1, NH * 4, hipMemcpyDeviceToDevice, stream);
  hipMemcpyAsync(bveccat + NV + NH, bh2, NH * 4, hipMemcpyDeviceToDevice, stream);

  const int M = S_LEN;
  dim3 g256(NV / 128, M / 128);
  dim3 g512(NH / 128, M / 128);
  dim3 gcat(NB / 128, M / 128);

  // 1) RNN pre-activations: Arnn = v_seq @ Wvu + bu (f32)
  gemm_bf16<F_F32, false><<<g256, blk, 0, stream>>>(
      vseq_bf, BTwvu, bu, nullptr, 0, nullptr, nullptr, Arnn, nullptr,
      nullptr, nullptr, 0.f, 0, 0, M, NV, NV, NV);
  // 2) chunked scan -> shifted (bf16)
  rnn_scan<<<dim3(S_LEN / 128), dim3(512), 0, stream>>>(Arnn, Wuu, shifted);
  // 3) all three dynamic biases in ONE GEMM: bias_cat = shifted @ Wycat^T + bveccat
  gemm_bf16<F_B16, false><<<gcat, blk, 0, stream>>>(
      shifted, Wycat, bveccat, nullptr, 0, bias_cat, nullptr, nullptr, nullptr,
      nullptr, nullptr, 0.f, 0, 0, M, NB, NR, NB);

  const int OFF_BV = 0, OFF_BH1 = NV, OFF_BH2 = NV + NH;

  // 4) RBM1 CD-5
  gemm_bf16<F_SAMP | F_H1 | F_FE, true><<<g512, blk, 0, stream>>>(
      vseq_bf, BTw1, nullptr, bias_cat + OFF_BH1, NB, sampA, h1buf, nullptr, nullptr,
      acc, nullptr, 1.0f, kk0[0], kk1[0], M, NH, NV, NH);
  for (int it = 0; it < CD_K; it++) {
    if (it > 0)
      gemm_bf16<F_SAMP, true><<<g512, blk, 0, stream>>>(
          sampB, BTw1, nullptr, bias_cat + OFF_BH1, NB, sampA, nullptr, nullptr, nullptr,
          nullptr, nullptr, 0.f, kk0[2 * it], kk1[2 * it], M, NH, NV, NH);
    if (it < CD_K - 1)
      gemm_bf16<F_SAMP, true><<<g256, blk, 0, stream>>>(
          sampA, BTw1t, nullptr, bias_cat + OFF_BV, NB, sampB, nullptr, nullptr, nullptr,
          nullptr, nullptr, 0.f, kk0[2 * it + 1], kk1[2 * it + 1], M, NV, NH, NV);
    else
      gemm_bf16<F_SAMP | F_MON, true><<<g256, blk, 0, stream>>>(
          sampA, BTw1t, nullptr, bias_cat + OFF_BV, NB, sampB, nullptr, nullptr, v_seq,
          nullptr, acc + 1, 0.f, kk0[2 * it + 1], kk1[2 * it + 1], M, NV, NH, NV);
  }
  // F1(sample): softplus sum only
  gemm_bf16<F_FE, true><<<g512, blk, 0, stream>>>(
      sampB, BTw1, nullptr, bias_cat + OFF_BH1, NB, nullptr, nullptr, nullptr, nullptr,
      acc, nullptr, -1.0f, 0, 0, M, NH, NV, NH);
  // F1 dot terms: -(v . bv_t) with sign
  dot_b16<<<dim3(1024), blk, 0, stream>>>(vseq_bf, bias_cat, (int)SN, 8, NB, OFF_BV,  1.0f, acc);
  dot_b16<<<dim3(1024), blk, 0, stream>>>(sampB,   bias_cat, (int)SN, 8, NB, OFF_BV, -1.0f, acc);

  // 5) RBM2 CD-5
  gemm_bf16<F_SAMP | F_FE, true><<<g512, blk, 0, stream>>>(
      h1buf, BTw2, nullptr, bias_cat + OFF_BH2, NB, sampA, nullptr, nullptr, nullptr,
      acc, nullptr, 1.0f, kk0[10], kk1[10], M, NH, NH, NH);
  for (int it = 0; it < CD_K; it++) {
    if (it > 0)
      gemm_bf16<F_SAMP, true><<<g512, blk, 0, stream>>>(
          sampB, BTw2, nullptr, bias_cat + OFF_BH2, NB, sampA, nullptr, nullptr, nullptr,
          nullptr, nullptr, 0.f, kk0[10 + 2 * it], kk1[10 + 2 * it], M, NH, NH, NH);
    gemm_bf16<F_SAMP, true><<<g512, blk, 0, stream>>>(
        sampA, BTw2t, nullptr, bias_cat + OFF_BH1, NB, sampB, nullptr, nullptr, nullptr,
        nullptr, nullptr, 0.f, kk0[11 + 2 * it], kk1[11 + 2 * it], M, NH, NH, NH);
  }
  // F2(sample)
  gemm_bf16<F_FE, true><<<g512, blk, 0, stream>>>(
      sampB, BTw2, nullptr, bias_cat + OFF_BH2, NB, nullptr, nullptr, nullptr, nullptr,
      acc, nullptr, -1.0f, 0, 0, M, NH, NH, NH);
  // F2 dot terms
  dot_b16<<<dim3(1024), blk, 0, stream>>>(h1buf, bias_cat, (int)SH, 9, NB, OFF_BH1,  1.0f, acc);
  dot_b16<<<dim3(1024), blk, 0, stream>>>(sampB, bias_cat, (int)SH, 9, NB, OFF_BH1, -1.0f, acc);

  finalize_kernel<<<1, 1, 0, stream>>>(acc, out);
}